// Round 9
// baseline (381.315 us; speedup 1.0000x reference)
//
#include <hip/hip_runtime.h>
#include <hip/hip_bf16.h>

// QuantizedLinear: T=8192 rows, N=K=4096, M=4096, RANK=64, CODESZ=8, CB=256.
// ws layout: x_bf16 [8192*4096] + W_eff bf16 [4096*4096] = 96 MiB.

typedef __attribute__((ext_vector_type(8))) short short8;
typedef __attribute__((ext_vector_type(16))) float f32x16;

#define T_ROWS 8192
#define NDIM   4096
#define MDIM   4096

// ---------------------------------------------------------------------------
// global -> LDS async copy, 16B/lane. LDS dest: wave-uniform base + lane*16.
__device__ __forceinline__ void gld_lds16(const void* g, void* lds_uniform) {
    __builtin_amdgcn_global_load_lds(
        (const __attribute__((address_space(1))) unsigned int*)(unsigned long long)(uintptr_t)g,
        (__attribute__((address_space(3))) unsigned int*)(unsigned int)(uintptr_t)lds_uniform,
        16, 0, 0);
}

__device__ __forceinline__ void bfly(float& a, float& b) {
    float s = a + b, d = a - b; a = s; b = d;
}

// ---------------------------------------------------------------------------
// 3-phase in-register FWHT-4096 (16 elems/thread, 2 syncthreads).
__device__ __forceinline__ void fwht16(float* v) {
#pragma unroll
    for (int h = 1; h <= 8; h <<= 1)
#pragma unroll
        for (int j = 0; j < 16; ++j)
            if (!(j & h)) bfly(v[j], v[j | h]);
}

// k1: x = fwht(input * SU) / 64, bf16 out.
__global__ __launch_bounds__(256) void fwht_in_kernel(
        const float* __restrict__ in, const float* __restrict__ SU,
        __hip_bfloat16* __restrict__ xout) {
    __shared__ float sh[4352];
    const int t = threadIdx.x;
    const size_t r = blockIdx.x;
    float v[16];
    {
        const float4* s4 = (const float4*)(in + (r << 12) + t * 16);
        const float4* u4 = (const float4*)(SU + t * 16);
#pragma unroll
        for (int q = 0; q < 4; ++q) {
            float4 a = s4[q], u = u4[q];
            v[4 * q + 0] = a.x * u.x; v[4 * q + 1] = a.y * u.y;
            v[4 * q + 2] = a.z * u.z; v[4 * q + 3] = a.w * u.w;
        }
    }
    fwht16(v);                                   // bits 0-3
#pragma unroll
    for (int j = 0; j < 16; ++j) sh[17 * t + j] = v[j];
    __syncthreads();
    const int baseB = (t & 15) + 272 * (t >> 4);
#pragma unroll
    for (int j = 0; j < 16; ++j) v[j] = sh[baseB + 17 * j];
    fwht16(v);                                   // bits 4-7
#pragma unroll
    for (int j = 0; j < 16; ++j) sh[baseB + 17 * j] = v[j];
    __syncthreads();
    const int baseC = t + (t >> 4);
#pragma unroll
    for (int j = 0; j < 16; ++j) v[j] = sh[baseC + 272 * j];
    fwht16(v);                                   // bits 8-11
    __hip_bfloat16* dst = xout + (r << 12);
#pragma unroll
    for (int j = 0; j < 16; ++j)
        dst[(j << 8) + t] = __float2bfloat16(v[j] * 0.015625f);
}

// k4: z = fwht(z) / 64 * SV, in place (f32).
__global__ __launch_bounds__(256) void fwht_out_kernel(
        float* __restrict__ z, const float* __restrict__ SV) {
    __shared__ float sh[4352];
    const int t = threadIdx.x;
    const size_t r = blockIdx.x;
    float* row = z + (r << 12);
    float v[16];
    {
        const float4* s4 = (const float4*)(row + t * 16);
#pragma unroll
        for (int q = 0; q < 4; ++q) {
            float4 a = s4[q];
            v[4 * q + 0] = a.x; v[4 * q + 1] = a.y;
            v[4 * q + 2] = a.z; v[4 * q + 3] = a.w;
        }
    }
    fwht16(v);
#pragma unroll
    for (int j = 0; j < 16; ++j) sh[17 * t + j] = v[j];
    __syncthreads();
    const int baseB = (t & 15) + 272 * (t >> 4);
#pragma unroll
    for (int j = 0; j < 16; ++j) v[j] = sh[baseB + 17 * j];
    fwht16(v);
#pragma unroll
    for (int j = 0; j < 16; ++j) sh[baseB + 17 * j] = v[j];
    __syncthreads();
    const int baseC = t + (t >> 4);
#pragma unroll
    for (int j = 0; j < 16; ++j) v[j] = sh[baseC + 272 * j];
    fwht16(v);
#pragma unroll
    for (int j = 0; j < 16; ++j)
        row[(j << 8) + t] = v[j] * 0.015625f * SV[(j << 8) + t];
}

// ---------------------------------------------------------------------------
// k2: W_eff = dequant + A@B, bf16. (unchanged)
__global__ __launch_bounds__(256) void dequant_kernel(
        const int* __restrict__ Qidxs, const float* __restrict__ cb,
        const float* __restrict__ Wscale, const float* __restrict__ A,
        const float* __restrict__ B, __hip_bfloat16* __restrict__ Weff) {
    __shared__ float At[64][68];
    __shared__ float Bs[64][68];
    __shared__ float cbs[2048];
    const int t = threadIdx.x;
    const int i0 = blockIdx.y * 64, j0 = blockIdx.x * 64;

    {
        const float* ga = A + (size_t)i0 * 64;
        const int r = t >> 2, kb = (t & 3) * 16;
#pragma unroll
        for (int j = 0; j < 16; ++j) At[kb + j][r] = ga[t * 16 + j];
        const int k = t >> 2, c0 = (t & 3) * 16;
        const float* gb = B + (size_t)k * NDIM + j0 + c0;
#pragma unroll
        for (int j = 0; j < 16; ++j) Bs[k][c0 + j] = gb[j];
#pragma unroll
        for (int j = 0; j < 8; ++j) cbs[t * 8 + j] = cb[t * 8 + j];
    }
    __syncthreads();

    const int ty = t >> 4, tx = t & 15;
    float acc[4][4];
#pragma unroll
    for (int a = 0; a < 4; ++a)
#pragma unroll
        for (int b = 0; b < 4; ++b) acc[a][b] = 0.f;

#pragma unroll 8
    for (int k = 0; k < 64; ++k) {
        const float4 av = *(const float4*)&At[k][ty * 4];
        const float4 bv = *(const float4*)&Bs[k][tx * 4];
        const float aa[4] = {av.x, av.y, av.z, av.w};
        const float bb[4] = {bv.x, bv.y, bv.z, bv.w};
#pragma unroll
        for (int ii = 0; ii < 4; ++ii)
#pragma unroll
            for (int jj = 0; jj < 4; ++jj) acc[ii][jj] += aa[ii] * bb[jj];
    }

    const float wsc = Wscale[0];
#pragma unroll
    for (int ii = 0; ii < 4; ++ii) {
        const int i = i0 + ty * 4 + ii;
        const int* qrow = Qidxs + (size_t)i * (NDIM / 8);
        union { __hip_bfloat16 h[4]; unsigned long long u; } pk;
#pragma unroll
        for (int jj = 0; jj < 4; ++jj) {
            const int j = j0 + tx * 4 + jj;
            const int idx = qrow[j >> 3];
            const float val = cbs[idx * 8 + (j & 7)] * wsc + acc[ii][jj];
            pk.h[jj] = __float2bfloat16(val);
        }
        *(unsigned long long*)&Weff[(size_t)i * NDIM + j0 + tx * 4] = pk.u;
    }
}

// ---------------------------------------------------------------------------
// k3: 256x256x(BK=64) bf16 NT GEMM — 32x32x16 MFMA, k-step pipeline, wave-
// staggered k-step order.
// 8 waves = 2M x 4N, per-wave C = 128x64 = 4x2 32x32 tiles (8 x f32x16 acc).
// K-tile = 4 k-steps of K=16; per k-step 4 A + 2 B b128 reads. Register sets
// S0,S1,S2 rotate (S0<->S1 swap per tile, S2 scratch):
//   entry: SA = last k-step of kt-1 (trailing), SB = first k-step of kt (PF'd)
//   MM(SA) | RD j1->SC | MM(SB j0) | RD j2->SA | MM(SC j1) | RD j3->SB |
//   MM(SA j2) | lgkm0 vm0 barrier | PF: RD j0(kt+1)->SA    [j3 trails]
// Staging: BOTH A and B staged exactly 1-ahead into the OTHER buffer at tile
// top (8 gld_lds), drained by the end-of-tile vmcnt(0) (loads are a full tile
// body old -> covered). No same-buffer overwrite while reading (fixes the
// round-8 race: old 2-ahead STB wrote CUR.B while ks1-3 still read it).
// Wave stagger: wm=1 waves (SIMD partners of wm=0 under round-robin wave->
// SIMD) process logical k-steps in order 2,3,0,1 so one wave's MFMA phase
// covers its partner's read burst (accumulation order is irrelevant).
__global__ __launch_bounds__(512, 2) void gemm256_kernel(
        const __hip_bfloat16* __restrict__ X, const __hip_bfloat16* __restrict__ W,
        float* __restrict__ Z) {
    __shared__ short smem[65536];   // 128 KiB: [buf2][A 16K | B 16K elems]

    const int b = blockIdx.x;                 // 512 blocks, 512 % 8 == 0
    const int swz = (b & 7) * 64 + (b >> 3);  // XCD-bijective
    const int bm = swz >> 4, bn = swz & 15;   // 32 x 16 tiles

    const int tid = threadIdx.x;
    const int lane = tid & 63, wid = tid >> 6;
    const int wm = wid >> 2, wn = wid & 3;
    const int l31 = lane & 31, kg = lane >> 5, le7 = lane & 7;
    const int rowV = l31 * 64;                           // row offset (elems)
    // wave-logical k-step j -> physical k-step (j + 2*wm) & 3; chunk(16B) =
    // ks*2 + kg, XOR'd with row&7 (= lane&7), *8 elems.
    const int ck0 = ((2 * ((0 + 2 * wm) & 3) + kg) ^ le7) << 3;
    const int ck1 = ((2 * ((1 + 2 * wm) & 3) + kg) ^ le7) << 3;
    const int ck2 = ((2 * ((2 + 2 * wm) & 3) + kg) ^ le7) << 3;
    const int ck3 = ((2 * ((3 + 2 * wm) & 3) + kg) ^ le7) << 3;
    const int wbase = wid << 9;

    const int grow = tid >> 3;
    const int scol = (((tid & 7) ^ (grow & 7)) << 3);    // pre-swizzled source col
    const __hip_bfloat16* gA = X + (size_t)(bm * 256 + grow) * NDIM + scol;
    const __hip_bfloat16* gB = W + (size_t)(bn * 256 + grow) * NDIM + scol;

#define STA2(OFS, H, Q, BUF) gld_lds16(gA + (size_t)(((H) * 128 + (Q) * 64) * NDIM) + (OFS), \
        &smem[(BUF) * 32768 + (H) * 8192 + (Q) * 4096 + wbase])
#define STB2(OFS, H, Q, BUF) gld_lds16(gB + (size_t)(((H) * 128 + (Q) * 64) * NDIM) + (OFS), \
        &smem[(BUF) * 32768 + 16384 + (H) * 8192 + (Q) * 4096 + wbase])
#define STAGE_A(OFS, BUF) do { STA2(OFS,0,0,BUF); STA2(OFS,0,1,BUF); \
                               STA2(OFS,1,0,BUF); STA2(OFS,1,1,BUF); } while (0)
#define STAGE_B(OFS, BUF) do { STB2(OFS,0,0,BUF); STB2(OFS,0,1,BUF); \
                               STB2(OFS,1,0,BUF); STB2(OFS,1,1,BUF); } while (0)

// read one k-step fragment set (4 A-frags m0..3 + 2 B-frags n0..1)
#define RD32_I(CK, BUF, A0,A1,A2,A3,B0,B1) do { \
    const short* aP = smem + (BUF) * 32768 + wm * 8192 + rowV + (CK); \
    const short* bP = smem + (BUF) * 32768 + 16384 + wn * 4096 + rowV + (CK); \
    A0 = *(const short8*)(aP); \
    A1 = *(const short8*)(aP + 2048); \
    A2 = *(const short8*)(aP + 4096); \
    A3 = *(const short8*)(aP + 6144); \
    B0 = *(const short8*)(bP); \
    B1 = *(const short8*)(bP + 2048); \
} while (0)
#define RD32(...) RD32_I(__VA_ARGS__)

#define MM32_I(A0,A1,A2,A3,B0,B1) do { \
    c00 = __builtin_amdgcn_mfma_f32_32x32x16_bf16(A0, B0, c00, 0, 0, 0); \
    c10 = __builtin_amdgcn_mfma_f32_32x32x16_bf16(A1, B0, c10, 0, 0, 0); \
    c01 = __builtin_amdgcn_mfma_f32_32x32x16_bf16(A0, B1, c01, 0, 0, 0); \
    c11 = __builtin_amdgcn_mfma_f32_32x32x16_bf16(A1, B1, c11, 0, 0, 0); \
    c20 = __builtin_amdgcn_mfma_f32_32x32x16_bf16(A2, B0, c20, 0, 0, 0); \
    c30 = __builtin_amdgcn_mfma_f32_32x32x16_bf16(A3, B0, c30, 0, 0, 0); \
    c21 = __builtin_amdgcn_mfma_f32_32x32x16_bf16(A2, B1, c21, 0, 0, 0); \
    c31 = __builtin_amdgcn_mfma_f32_32x32x16_bf16(A3, B1, c31, 0, 0, 0); \
} while (0)
#define MM32(...) MM32_I(__VA_ARGS__)

#define SARGS0 s0a0,s0a1,s0a2,s0a3,s0b0,s0b1
#define SARGS1 s1a0,s1a1,s1a2,s1a3,s1b0,s1b1
#define SARGS2 s2a0,s2a1,s2a2,s2a3,s2b0,s2b1

#define TILE32_I(CUR, M3P, DO_ST, DO_PF, LAST, \
               SA0,SA1,SA2,SA3,SA4,SA5, SB0,SB1,SB2,SB3,SB4,SB5, \
               SC0,SC1,SC2,SC3,SC4,SC5) do { \
    if (DO_ST) { STAGE_A(64, 1 - (CUR)); STAGE_B(64, 1 - (CUR)); } \
    if (M3P) MM32(SA0,SA1,SA2,SA3,SA4,SA5);             /* trailing j3(kt-1) */ \
    RD32(ck1, CUR, SC0,SC1,SC2,SC3,SC4,SC5); \
    MM32(SB0,SB1,SB2,SB3,SB4,SB5);                      /* j0(kt) */ \
    RD32(ck2, CUR, SA0,SA1,SA2,SA3,SA4,SA5); \
    MM32(SC0,SC1,SC2,SC3,SC4,SC5);                      /* j1(kt) */ \
    RD32(ck3, CUR, SB0,SB1,SB2,SB3,SB4,SB5); \
    MM32(SA0,SA1,SA2,SA3,SA4,SA5);                      /* j2(kt) */ \
    if (!(LAST)) { \
        asm volatile("s_waitcnt lgkmcnt(0)" ::: "memory"); \
        asm volatile("s_waitcnt vmcnt(0)" ::: "memory"); \
        __builtin_amdgcn_s_barrier(); \
        asm volatile("" ::: "memory"); \
    } \
    if (DO_PF) RD32(ck0, 1 - (CUR), SA0,SA1,SA2,SA3,SA4,SA5);  /* j0(kt+1) */ \
    gA += 64; gB += 64; \
} while (0)
#define TILE32(...) TILE32_I(__VA_ARGS__)

    f32x16 c00 = {0}, c01 = {0}, c10 = {0}, c11 = {0};
    f32x16 c20 = {0}, c21 = {0}, c30 = {0}, c31 = {0};
    short8 s0a0, s0a1, s0a2, s0a3, s0b0, s0b1;
    short8 s1a0, s1a1, s1a2, s1a3, s1b0, s1b1;
    short8 s2a0, s2a1, s2a2, s2a3, s2b0, s2b1;

    // prologue: stage kt0 (A+B) -> buf0; publish; prefetch j0(0) -> S1
    STAGE_A(0, 0);
    STAGE_B(0, 0);
    asm volatile("s_waitcnt vmcnt(0)" ::: "memory");
    __builtin_amdgcn_s_barrier();
    asm volatile("" ::: "memory");
    RD32(ck0, 0, SARGS1);

    // kt = 0 (no trailing cluster)
    TILE32(0, 0, 1, 1, 0, SARGS0, SARGS1, SARGS2);
    for (int i = 0; i < 31; ++i) {              // kt = 1..62 (31 odd/even pairs)
        TILE32(1, 1, 1, 1, 0, SARGS1, SARGS0, SARGS2);
        TILE32(0, 1, 1, 1, 0, SARGS0, SARGS1, SARGS2);
    }
    TILE32(1, 1, 0, 0, 1, SARGS1, SARGS0, SARGS2);   // kt = 63: compute only
    MM32(SARGS0);                                     // trailing j3(63)

    // epilogue: 32x32 C/D layout: col = lane&31, row = (reg&3)+8*(reg>>2)+4*(lane>>5)
    const size_t r0 = (size_t)bm * 256 + wm * 128 + 4 * (lane >> 5);
    const size_t cb0 = (size_t)bn * 256 + wn * 64 + l31;
#define CWR(CC, M, N) do { \
    _Pragma("unroll") \
    for (int rg = 0; rg < 16; ++rg) \
        Z[(r0 + (M) * 32 + (rg & 3) + 8 * (rg >> 2)) * MDIM + cb0 + (N) * 32] = CC[rg]; \
} while (0)
    CWR(c00, 0, 0); CWR(c01, 0, 1);
    CWR(c10, 1, 0); CWR(c11, 1, 1);
    CWR(c20, 2, 0); CWR(c21, 2, 1);
    CWR(c30, 3, 0); CWR(c31, 3, 1);
}

// ---------------------------------------------------------------------------
extern "C" void kernel_launch(void* const* d_in, const int* in_sizes, int n_in,
                              void* d_out, int out_size, void* d_ws, size_t ws_size,
                              hipStream_t stream) {
    const float* input  = (const float*)d_in[0];
    const int*   Qidxs  = (const int*)d_in[1];
    const float* cbvals = (const float*)d_in[2];
    const float* SU     = (const float*)d_in[3];
    const float* SV     = (const float*)d_in[4];
    const float* Wscale = (const float*)d_in[5];
    const float* A      = (const float*)d_in[6];
    const float* B      = (const float*)d_in[7];
    float* out = (float*)d_out;

    __hip_bfloat16* xbf = (__hip_bfloat16*)d_ws;
    __hip_bfloat16* wbf = (__hip_bfloat16*)((char*)d_ws + (size_t)T_ROWS * NDIM * 2);

    fwht_in_kernel<<<T_ROWS, 256, 0, stream>>>(input, SU, xbf);
    dequant_kernel<<<dim3(MDIM / 64, MDIM / 64), 256, 0, stream>>>(
        Qidxs, cbvals, Wscale, A, B, wbf);
    gemm256_kernel<<<(T_ROWS / 256) * (MDIM / 256), 512, 0, stream>>>(xbf, wbf, out);
    fwht_out_kernel<<<T_ROWS, 256, 0, stream>>>(out, SV);
}

// Round 10
// 378.433 us; speedup vs baseline: 1.0076x; 1.0076x over previous
//
#include <hip/hip_runtime.h>
#include <hip/hip_bf16.h>

// QuantizedLinear: T=8192 rows, N=K=4096, M=4096, RANK=64, CODESZ=8, CB=256.
// ws layout: x_bf16 [8192*4096] + W_eff bf16 [4096*4096] = 96 MiB.

typedef __attribute__((ext_vector_type(8))) short short8;
typedef __attribute__((ext_vector_type(16))) float f32x16;

#define T_ROWS 8192
#define NDIM   4096
#define MDIM   4096

// ---------------------------------------------------------------------------
// global -> LDS async copy, 16B/lane. LDS dest: wave-uniform base + lane*16.
__device__ __forceinline__ void gld_lds16(const void* g, void* lds_uniform) {
    __builtin_amdgcn_global_load_lds(
        (const __attribute__((address_space(1))) unsigned int*)(unsigned long long)(uintptr_t)g,
        (__attribute__((address_space(3))) unsigned int*)(unsigned int)(uintptr_t)lds_uniform,
        16, 0, 0);
}

__device__ __forceinline__ void bfly(float& a, float& b) {
    float s = a + b, d = a - b; a = s; b = d;
}

// ---------------------------------------------------------------------------
// 3-phase in-register FWHT-4096 (16 elems/thread, 2 syncthreads).
__device__ __forceinline__ void fwht16(float* v) {
#pragma unroll
    for (int h = 1; h <= 8; h <<= 1)
#pragma unroll
        for (int j = 0; j < 16; ++j)
            if (!(j & h)) bfly(v[j], v[j | h]);
}

// k1: x = fwht(input * SU) / 64, bf16 out.
__global__ __launch_bounds__(256) void fwht_in_kernel(
        const float* __restrict__ in, const float* __restrict__ SU,
        __hip_bfloat16* __restrict__ xout) {
    __shared__ float sh[4352];
    const int t = threadIdx.x;
    const size_t r = blockIdx.x;
    float v[16];
    {
        const float4* s4 = (const float4*)(in + (r << 12) + t * 16);
        const float4* u4 = (const float4*)(SU + t * 16);
#pragma unroll
        for (int q = 0; q < 4; ++q) {
            float4 a = s4[q], u = u4[q];
            v[4 * q + 0] = a.x * u.x; v[4 * q + 1] = a.y * u.y;
            v[4 * q + 2] = a.z * u.z; v[4 * q + 3] = a.w * u.w;
        }
    }
    fwht16(v);                                   // bits 0-3
#pragma unroll
    for (int j = 0; j < 16; ++j) sh[17 * t + j] = v[j];
    __syncthreads();
    const int baseB = (t & 15) + 272 * (t >> 4);
#pragma unroll
    for (int j = 0; j < 16; ++j) v[j] = sh[baseB + 17 * j];
    fwht16(v);                                   // bits 4-7
#pragma unroll
    for (int j = 0; j < 16; ++j) sh[baseB + 17 * j] = v[j];
    __syncthreads();
    const int baseC = t + (t >> 4);
#pragma unroll
    for (int j = 0; j < 16; ++j) v[j] = sh[baseC + 272 * j];
    fwht16(v);                                   // bits 8-11
    __hip_bfloat16* dst = xout + (r << 12);
#pragma unroll
    for (int j = 0; j < 16; ++j)
        dst[(j << 8) + t] = __float2bfloat16(v[j] * 0.015625f);
}

// k4: z = fwht(z) / 64 * SV, in place (f32).
__global__ __launch_bounds__(256) void fwht_out_kernel(
        float* __restrict__ z, const float* __restrict__ SV) {
    __shared__ float sh[4352];
    const int t = threadIdx.x;
    const size_t r = blockIdx.x;
    float* row = z + (r << 12);
    float v[16];
    {
        const float4* s4 = (const float4*)(row + t * 16);
#pragma unroll
        for (int q = 0; q < 4; ++q) {
            float4 a = s4[q];
            v[4 * q + 0] = a.x; v[4 * q + 1] = a.y;
            v[4 * q + 2] = a.z; v[4 * q + 3] = a.w;
        }
    }
    fwht16(v);
#pragma unroll
    for (int j = 0; j < 16; ++j) sh[17 * t + j] = v[j];
    __syncthreads();
    const int baseB = (t & 15) + 272 * (t >> 4);
#pragma unroll
    for (int j = 0; j < 16; ++j) v[j] = sh[baseB + 17 * j];
    fwht16(v);
#pragma unroll
    for (int j = 0; j < 16; ++j) sh[baseB + 17 * j] = v[j];
    __syncthreads();
    const int baseC = t + (t >> 4);
#pragma unroll
    for (int j = 0; j < 16; ++j) v[j] = sh[baseC + 272 * j];
    fwht16(v);
#pragma unroll
    for (int j = 0; j < 16; ++j)
        row[(j << 8) + t] = v[j] * 0.015625f * SV[(j << 8) + t];
}

// ---------------------------------------------------------------------------
// k2: W_eff = dequant + A@B, bf16. (unchanged)
__global__ __launch_bounds__(256) void dequant_kernel(
        const int* __restrict__ Qidxs, const float* __restrict__ cb,
        const float* __restrict__ Wscale, const float* __restrict__ A,
        const float* __restrict__ B, __hip_bfloat16* __restrict__ Weff) {
    __shared__ float At[64][68];
    __shared__ float Bs[64][68];
    __shared__ float cbs[2048];
    const int t = threadIdx.x;
    const int i0 = blockIdx.y * 64, j0 = blockIdx.x * 64;

    {
        const float* ga = A + (size_t)i0 * 64;
        const int r = t >> 2, kb = (t & 3) * 16;
#pragma unroll
        for (int j = 0; j < 16; ++j) At[kb + j][r] = ga[t * 16 + j];
        const int k = t >> 2, c0 = (t & 3) * 16;
        const float* gb = B + (size_t)k * NDIM + j0 + c0;
#pragma unroll
        for (int j = 0; j < 16; ++j) Bs[k][c0 + j] = gb[j];
#pragma unroll
        for (int j = 0; j < 8; ++j) cbs[t * 8 + j] = cb[t * 8 + j];
    }
    __syncthreads();

    const int ty = t >> 4, tx = t & 15;
    float acc[4][4];
#pragma unroll
    for (int a = 0; a < 4; ++a)
#pragma unroll
        for (int b = 0; b < 4; ++b) acc[a][b] = 0.f;

#pragma unroll 8
    for (int k = 0; k < 64; ++k) {
        const float4 av = *(const float4*)&At[k][ty * 4];
        const float4 bv = *(const float4*)&Bs[k][tx * 4];
        const float aa[4] = {av.x, av.y, av.z, av.w};
        const float bb[4] = {bv.x, bv.y, bv.z, bv.w};
#pragma unroll
        for (int ii = 0; ii < 4; ++ii)
#pragma unroll
            for (int jj = 0; jj < 4; ++jj) acc[ii][jj] += aa[ii] * bb[jj];
    }

    const float wsc = Wscale[0];
#pragma unroll
    for (int ii = 0; ii < 4; ++ii) {
        const int i = i0 + ty * 4 + ii;
        const int* qrow = Qidxs + (size_t)i * (NDIM / 8);
        union { __hip_bfloat16 h[4]; unsigned long long u; } pk;
#pragma unroll
        for (int jj = 0; jj < 4; ++jj) {
            const int j = j0 + tx * 4 + jj;
            const int idx = qrow[j >> 3];
            const float val = cbs[idx * 8 + (j & 7)] * wsc + acc[ii][jj];
            pk.h[jj] = __float2bfloat16(val);
        }
        *(unsigned long long*)&Weff[(size_t)i * NDIM + j0 + tx * 4] = pk.u;
    }
}

// ---------------------------------------------------------------------------
// k3: 256x256x(BK=64) bf16 NT GEMM — 32x32x16 MFMA, k-step pipeline, wave-
// staggered k-step order, CONFLICT-FREE swizzle.
// Swizzle: stored chunk_s(row, c) = c ^ (row&7) ^ ((row>>4)&3). The (row>>4)
// term makes the bank mapping differ between lanes 0-15 and 16-31 (rows are
// lane&31; row stride 128B leaves banks untouched) — this is the profile that
// measured ZERO conflicts in rounds 2-6; round 9 dropped it (2.5e7 conflicts).
// Read side: every fragment base is 32-row aligned; even 32-row blocks
// (A0,A2,B0) read chunk ^ ((lane>>4)&1); odd blocks (A1,A3,B1) additionally
// XOR 2 (element offset ^16).
__global__ __launch_bounds__(512, 2) void gemm256_kernel(
        const __hip_bfloat16* __restrict__ X, const __hip_bfloat16* __restrict__ W,
        float* __restrict__ Z) {
    __shared__ short smem[65536];   // 128 KiB: [buf2][A 16K | B 16K elems]

    const int b = blockIdx.x;                 // 512 blocks, 512 % 8 == 0
    const int swz = (b & 7) * 64 + (b >> 3);  // XCD-bijective
    const int bm = swz >> 4, bn = swz & 15;   // 32 x 16 tiles

    const int tid = threadIdx.x;
    const int lane = tid & 63, wid = tid >> 6;
    const int wm = wid >> 2, wn = wid & 3;
    const int l31 = lane & 31, kg = lane >> 5, le7 = lane & 7;
    const int rowV = l31 * 64;                           // row offset (elems)
    // read-side XOR: le7 (row&7) + per-16-lane group bit ((row>>4)&1)
    const int xr = le7 ^ ((lane >> 4) & 1);
    // wave-logical k-step j -> physical (j + 2*wm) & 3; chunk = ks*2+kg
    const int ck0 = ((2 * ((0 + 2 * wm) & 3) + kg) ^ xr) << 3;
    const int ck1 = ((2 * ((1 + 2 * wm) & 3) + kg) ^ xr) << 3;
    const int ck2 = ((2 * ((2 + 2 * wm) & 3) + kg) ^ xr) << 3;
    const int ck3 = ((2 * ((3 + 2 * wm) & 3) + kg) ^ xr) << 3;
    const int wbase = wid << 9;

    const int grow = tid >> 3;
    // pre-swizzled source col: chunk_s = tid&7 holds column (tid&7)^f(grow),
    // f(row) = (row&7) ^ ((row>>4)&3)  (Q*64/H*128 offsets preserve f)
    const int scol = (((tid & 7) ^ (grow & 7) ^ ((grow >> 4) & 3)) << 3);
    const __hip_bfloat16* gA = X + (size_t)(bm * 256 + grow) * NDIM + scol;
    const __hip_bfloat16* gB = W + (size_t)(bn * 256 + grow) * NDIM + scol;

#define STA2(OFS, H, Q, BUF) gld_lds16(gA + (size_t)(((H) * 128 + (Q) * 64) * NDIM) + (OFS), \
        &smem[(BUF) * 32768 + (H) * 8192 + (Q) * 4096 + wbase])
#define STB2(OFS, H, Q, BUF) gld_lds16(gB + (size_t)(((H) * 128 + (Q) * 64) * NDIM) + (OFS), \
        &smem[(BUF) * 32768 + 16384 + (H) * 8192 + (Q) * 4096 + wbase])
#define STAGE_A(OFS, BUF) do { STA2(OFS,0,0,BUF); STA2(OFS,0,1,BUF); \
                               STA2(OFS,1,0,BUF); STA2(OFS,1,1,BUF); } while (0)
#define STAGE_B(OFS, BUF) do { STB2(OFS,0,0,BUF); STB2(OFS,0,1,BUF); \
                               STB2(OFS,1,0,BUF); STB2(OFS,1,1,BUF); } while (0)

// read one k-step fragment set; even 32-row blocks use CK, odd use CK^16
#define RD32_I(CK, BUF, A0,A1,A2,A3,B0,B1) do { \
    const short* aP = smem + (BUF) * 32768 + wm * 8192 + rowV; \
    const short* bP = smem + (BUF) * 32768 + 16384 + wn * 4096 + rowV; \
    A0 = *(const short8*)(aP + (CK)); \
    A1 = *(const short8*)(aP + 2048 + ((CK) ^ 16)); \
    A2 = *(const short8*)(aP + 4096 + (CK)); \
    A3 = *(const short8*)(aP + 6144 + ((CK) ^ 16)); \
    B0 = *(const short8*)(bP + (CK)); \
    B1 = *(const short8*)(bP + 2048 + ((CK) ^ 16)); \
} while (0)
#define RD32(...) RD32_I(__VA_ARGS__)

#define MM32_I(A0,A1,A2,A3,B0,B1) do { \
    c00 = __builtin_amdgcn_mfma_f32_32x32x16_bf16(A0, B0, c00, 0, 0, 0); \
    c10 = __builtin_amdgcn_mfma_f32_32x32x16_bf16(A1, B0, c10, 0, 0, 0); \
    c01 = __builtin_amdgcn_mfma_f32_32x32x16_bf16(A0, B1, c01, 0, 0, 0); \
    c11 = __builtin_amdgcn_mfma_f32_32x32x16_bf16(A1, B1, c11, 0, 0, 0); \
    c20 = __builtin_amdgcn_mfma_f32_32x32x16_bf16(A2, B0, c20, 0, 0, 0); \
    c30 = __builtin_amdgcn_mfma_f32_32x32x16_bf16(A3, B0, c30, 0, 0, 0); \
    c21 = __builtin_amdgcn_mfma_f32_32x32x16_bf16(A2, B1, c21, 0, 0, 0); \
    c31 = __builtin_amdgcn_mfma_f32_32x32x16_bf16(A3, B1, c31, 0, 0, 0); \
} while (0)
#define MM32(...) MM32_I(__VA_ARGS__)

#define SARGS0 s0a0,s0a1,s0a2,s0a3,s0b0,s0b1
#define SARGS1 s1a0,s1a1,s1a2,s1a3,s1b0,s1b1
#define SARGS2 s2a0,s2a1,s2a2,s2a3,s2b0,s2b1

#define TILE32_I(CUR, M3P, DO_ST, DO_PF, LAST, \
               SA0,SA1,SA2,SA3,SA4,SA5, SB0,SB1,SB2,SB3,SB4,SB5, \
               SC0,SC1,SC2,SC3,SC4,SC5) do { \
    if (DO_ST) { STAGE_A(64, 1 - (CUR)); STAGE_B(64, 1 - (CUR)); } \
    if (M3P) MM32(SA0,SA1,SA2,SA3,SA4,SA5);             /* trailing j3(kt-1) */ \
    RD32(ck1, CUR, SC0,SC1,SC2,SC3,SC4,SC5); \
    MM32(SB0,SB1,SB2,SB3,SB4,SB5);                      /* j0(kt) */ \
    RD32(ck2, CUR, SA0,SA1,SA2,SA3,SA4,SA5); \
    MM32(SC0,SC1,SC2,SC3,SC4,SC5);                      /* j1(kt) */ \
    RD32(ck3, CUR, SB0,SB1,SB2,SB3,SB4,SB5); \
    MM32(SA0,SA1,SA2,SA3,SA4,SA5);                      /* j2(kt) */ \
    if (!(LAST)) { \
        asm volatile("s_waitcnt lgkmcnt(0)" ::: "memory"); \
        asm volatile("s_waitcnt vmcnt(0)" ::: "memory"); \
        __builtin_amdgcn_s_barrier(); \
        asm volatile("" ::: "memory"); \
    } \
    if (DO_PF) RD32(ck0, 1 - (CUR), SA0,SA1,SA2,SA3,SA4,SA5);  /* j0(kt+1) */ \
    gA += 64; gB += 64; \
} while (0)
#define TILE32(...) TILE32_I(__VA_ARGS__)

    f32x16 c00 = {0}, c01 = {0}, c10 = {0}, c11 = {0};
    f32x16 c20 = {0}, c21 = {0}, c30 = {0}, c31 = {0};
    short8 s0a0, s0a1, s0a2, s0a3, s0b0, s0b1;
    short8 s1a0, s1a1, s1a2, s1a3, s1b0, s1b1;
    short8 s2a0, s2a1, s2a2, s2a3, s2b0, s2b1;

    // prologue: stage kt0 (A+B) -> buf0; publish; prefetch j0(0) -> S1
    STAGE_A(0, 0);
    STAGE_B(0, 0);
    asm volatile("s_waitcnt vmcnt(0)" ::: "memory");
    __builtin_amdgcn_s_barrier();
    asm volatile("" ::: "memory");
    RD32(ck0, 0, SARGS1);

    // kt = 0 (no trailing cluster)
    TILE32(0, 0, 1, 1, 0, SARGS0, SARGS1, SARGS2);
    for (int i = 0; i < 31; ++i) {              // kt = 1..62 (31 odd/even pairs)
        TILE32(1, 1, 1, 1, 0, SARGS1, SARGS0, SARGS2);
        TILE32(0, 1, 1, 1, 0, SARGS0, SARGS1, SARGS2);
    }
    TILE32(1, 1, 0, 0, 1, SARGS1, SARGS0, SARGS2);   // kt = 63: compute only
    MM32(SARGS0);                                     // trailing j3(63)

    // epilogue: 32x32 C/D layout: col = lane&31, row = (reg&3)+8*(reg>>2)+4*(lane>>5)
    const size_t r0 = (size_t)bm * 256 + wm * 128 + 4 * (lane >> 5);
    const size_t cb0 = (size_t)bn * 256 + wn * 64 + l31;
#define CWR(CC, M, N) do { \
    _Pragma("unroll") \
    for (int rg = 0; rg < 16; ++rg) \
        Z[(r0 + (M) * 32 + (rg & 3) + 8 * (rg >> 2)) * MDIM + cb0 + (N) * 32] = CC[rg]; \
} while (0)
    CWR(c00, 0, 0); CWR(c01, 0, 1);
    CWR(c10, 1, 0); CWR(c11, 1, 1);
    CWR(c20, 2, 0); CWR(c21, 2, 1);
    CWR(c30, 3, 0); CWR(c31, 3, 1);
}

// ---------------------------------------------------------------------------
extern "C" void kernel_launch(void* const* d_in, const int* in_sizes, int n_in,
                              void* d_out, int out_size, void* d_ws, size_t ws_size,
                              hipStream_t stream) {
    const float* input  = (const float*)d_in[0];
    const int*   Qidxs  = (const int*)d_in[1];
    const float* cbvals = (const float*)d_in[2];
    const float* SU     = (const float*)d_in[3];
    const float* SV     = (const float*)d_in[4];
    const float* Wscale = (const float*)d_in[5];
    const float* A      = (const float*)d_in[6];
    const float* B      = (const float*)d_in[7];
    float* out = (float*)d_out;

    __hip_bfloat16* xbf = (__hip_bfloat16*)d_ws;
    __hip_bfloat16* wbf = (__hip_bfloat16*)((char*)d_ws + (size_t)T_ROWS * NDIM * 2);

    fwht_in_kernel<<<T_ROWS, 256, 0, stream>>>(input, SU, xbf);
    dequant_kernel<<<dim3(MDIM / 64, MDIM / 64), 256, 0, stream>>>(
        Qidxs, cbvals, Wscale, A, B, wbf);
    gemm256_kernel<<<(T_ROWS / 256) * (MDIM / 256), 512, 0, stream>>>(xbf, wbf, out);
    fwht_out_kernel<<<T_ROWS, 256, 0, stream>>>(out, SV);
}